// Round 8
// baseline (212.710 us; speedup 1.0000x reference)
//
#include <hip/hip_runtime.h>

// ---------------------------------------------------------------------------
// res_rand_GAE round 8: L2-resident chunked CSR gather (4 passes of 32
// features; 3.2 MB chunk table < 4 MB per-XCD L2; quarter-wave per node).
// Gather tables stored chunked [4][N][32]; GEMMs adapted to read/write the
// chunked layout. Outputs: x [N,128] ++ A [N,1] fp32 in d_out.
// ---------------------------------------------------------------------------

typedef unsigned short u16;
typedef short bf16x8 __attribute__((ext_vector_type(8)));
typedef unsigned short us8 __attribute__((ext_vector_type(8)));
typedef float f32x4 __attribute__((ext_vector_type(4)));

static inline int cdiv_ll(long long a, long long b) { return (int)((a + b - 1) / b); }

__device__ inline float bf2f(u16 u) {
    union { unsigned int i; float f; } v; v.i = ((unsigned int)u) << 16; return v.f;
}
__device__ inline u16 f2bf(float x) {   // round-to-nearest-even
    union { float f; unsigned int i; } v; v.f = x;
    unsigned int r = v.i + 0x7fffu + ((v.i >> 16) & 1u);
    return (u16)(r >> 16);
}

// ---- fused setup: cnt=0, Aout=bfc2, emb->bf16 (chunked), W^T's -------------

__global__ __launch_bounds__(256) void setup_kernel(const float* __restrict__ emb,
                                                    const float* __restrict__ W1,
                                                    const float* __restrict__ W2,
                                                    const float* __restrict__ Wres,
                                                    const float* __restrict__ Wfc1,
                                                    const float* __restrict__ bfc2,
                                                    u16* __restrict__ embb,   // [4][N][32]
                                                    u16* __restrict__ W1t,
                                                    u16* __restrict__ Wct,
                                                    u16* __restrict__ Wfc1t,
                                                    int* __restrict__ cnt,
                                                    float* __restrict__ Aout,
                                                    int N) {
    long long r = (long long)blockIdx.x * 256 + threadIdx.x;
    const long long nf2b = (long long)N * 32;          // float4s of emb
    if (r < nf2b) {
        int node = (int)(r >> 5);
        int f    = (int)(r & 31) * 4;                  // feature, mult of 4
        float4 v = ((const float4*)emb)[r];
        uint2 o;
        o.x = (unsigned)f2bf(v.x) | ((unsigned)f2bf(v.y) << 16);
        o.y = (unsigned)f2bf(v.z) | ((unsigned)f2bf(v.w) << 16);
        *(uint2*)(embb + ((size_t)(f >> 5) * N + node) * 32 + (f & 31)) = o;
        return;
    }
    r -= nf2b;
    if (r < 512 * 128) {                               // W1t[n*128+k] = W1[k*512+n]
        int n = (int)(r / 128), k = (int)(r % 128);
        W1t[r] = f2bf(W1[(size_t)k * 512 + n]);
        return;
    }
    r -= 512 * 128;
    if (r < 256 * 512) {                               // Wct[n*512+k]
        int n = (int)(r / 512), k = (int)(r % 512);
        float v = (n < 128) ? W2[(size_t)k * 128 + n] : Wres[(size_t)k * 128 + (n - 128)];
        Wct[r] = f2bf(v);
        return;
    }
    r -= 256 * 512;
    if (r < 256 * 128) {                               // Wfc1t[n*128+k]
        int n = (int)(r / 128), k = (int)(r % 128);
        Wfc1t[r] = f2bf(Wfc1[(size_t)k * 256 + n]);
        return;
    }
    r -= 256 * 128;
    if (r < N) { cnt[(int)r] = 0; return; }
    r -= N;
    if (r < N) Aout[(int)r] = bfc2[0];
}

// ---- CSR build -------------------------------------------------------------

__global__ __launch_bounds__(256) void hist_kernel(const int* __restrict__ dst,
                                                   int* __restrict__ cnt, int E) {
    int e = blockIdx.x * 256 + threadIdx.x;
    if (e < E) atomicAdd(&cnt[dst[e]], 1);
}

__global__ __launch_bounds__(256) void scanA_kernel(const int* __restrict__ cnt,
                                                    int* __restrict__ excl,
                                                    int* __restrict__ bsum, int N) {
    __shared__ int tmp[256];
    int i = blockIdx.x * 256 + threadIdx.x;
    int v = (i < N) ? cnt[i] : 0;
    tmp[threadIdx.x] = v;
    __syncthreads();
    for (int o = 1; o < 256; o <<= 1) {
        int t = (threadIdx.x >= (unsigned)o) ? tmp[threadIdx.x - o] : 0;
        __syncthreads();
        tmp[threadIdx.x] += t;
        __syncthreads();
    }
    if (i < N) excl[i] = tmp[threadIdx.x] - v;
    if (threadIdx.x == 255) bsum[blockIdx.x] = tmp[255];
}

__global__ __launch_bounds__(256) void scanB_kernel(int* __restrict__ bsum, int nb) {
    __shared__ int tmp[256];
    int v = (threadIdx.x < (unsigned)nb) ? bsum[threadIdx.x] : 0;
    tmp[threadIdx.x] = v;
    __syncthreads();
    for (int o = 1; o < 256; o <<= 1) {
        int t = (threadIdx.x >= (unsigned)o) ? tmp[threadIdx.x - o] : 0;
        __syncthreads();
        tmp[threadIdx.x] += t;
        __syncthreads();
    }
    if (threadIdx.x < (unsigned)nb) bsum[threadIdx.x] = tmp[threadIdx.x] - v;
}

__global__ __launch_bounds__(256) void scanC_kernel(const int* __restrict__ excl,
                                                    const int* __restrict__ bsum,
                                                    const int* __restrict__ cnt,
                                                    int* __restrict__ rowptr,
                                                    int* __restrict__ cursor,
                                                    float* __restrict__ dinv,
                                                    int N, int E) {
    int i = blockIdx.x * 256 + threadIdx.x;
    if (i < N) {
        int r = excl[i] + bsum[blockIdx.x];
        rowptr[i] = r;
        cursor[i] = r;
        dinv[i] = rsqrtf((float)cnt[i] + 2.0f);
    }
    if (i == 0) rowptr[N] = E;
}

__global__ __launch_bounds__(256) void fill_kernel(const int* __restrict__ src,
                                                   const int* __restrict__ dst,
                                                   const float* __restrict__ dinv,
                                                   int* __restrict__ cursor,
                                                   int* __restrict__ csr_src,
                                                   float* __restrict__ csr_w, int E) {
    int e = blockIdx.x * 256 + threadIdx.x;
    if (e >= E) return;
    int s = src[e], d = dst[e];
    int idx = atomicAdd(&cursor[d], 1);
    csr_src[idx] = s;
    csr_w[idx] = dinv[s] * dinv[d];
}

// ---- chunked CSR aggregation: quarter-wave per node, 32 features/pass ------
// hb chunked [4][N][32] bf16. grid = (ceil(N/16), 4); chunk table 3.2 MB
// stays L2-resident per XCD during its phase.
// FINAL=0: out chunked [4][N][32] bf16 (aggE -> GEMM1 A operand)
// FINAL=1: x = relu(agg + b2) + hres + bres -> xout fp32 [N][128] + xb bf16

#define AGGC_EDGE(SR, WR)                                                      \
    {                                                                          \
        unsigned int vv = hp[(size_t)(SR) * 16 + l];                           \
        ax = fmaf(bf2f((u16)vv), (WR), ax);                                    \
        ay = fmaf(bf2f((u16)(vv >> 16)), (WR), ay);                            \
    }

template <int FINAL>
__global__ __launch_bounds__(256) void aggc_kernel(const u16* __restrict__ hb,
                                                   const int* __restrict__ rowptr,
                                                   const int* __restrict__ csr_src,
                                                   const float* __restrict__ csr_w,
                                                   const float* __restrict__ dinv,
                                                   const float* __restrict__ b2,
                                                   const float* __restrict__ bres,
                                                   float* __restrict__ xout,
                                                   u16* __restrict__ outb,
                                                   int N) {
    const int l = threadIdx.x & 15;
    const int node = blockIdx.x * 16 + (threadIdx.x >> 4);
    const int chunk = blockIdx.y;
    if (node >= N) return;
    const unsigned int* hp = (const unsigned int*)hb + (size_t)chunk * N * 16;

    float dv = dinv[node];
    float c0 = 2.0f * dv * dv;
    unsigned int hv = hp[(size_t)node * 16 + l];
    float ax = bf2f((u16)hv) * c0;
    float ay = bf2f((u16)(hv >> 16)) * c0;

    int e = rowptr[node], e1 = rowptr[node + 1];
    for (; e + 7 < e1; e += 8) {
        int s0 = csr_src[e + 0], s1 = csr_src[e + 1], s2 = csr_src[e + 2], s3 = csr_src[e + 3];
        int s4 = csr_src[e + 4], s5 = csr_src[e + 5], s6 = csr_src[e + 6], s7 = csr_src[e + 7];
        float w0 = csr_w[e + 0], w1 = csr_w[e + 1], w2 = csr_w[e + 2], w3 = csr_w[e + 3];
        float w4 = csr_w[e + 4], w5 = csr_w[e + 5], w6 = csr_w[e + 6], w7 = csr_w[e + 7];
        AGGC_EDGE(s0, w0); AGGC_EDGE(s1, w1); AGGC_EDGE(s2, w2); AGGC_EDGE(s3, w3);
        AGGC_EDGE(s4, w4); AGGC_EDGE(s5, w5); AGGC_EDGE(s6, w6); AGGC_EDGE(s7, w7);
    }
    if (e + 3 < e1) {
        int s0 = csr_src[e + 0], s1 = csr_src[e + 1], s2 = csr_src[e + 2], s3 = csr_src[e + 3];
        float w0 = csr_w[e + 0], w1 = csr_w[e + 1], w2 = csr_w[e + 2], w3 = csr_w[e + 3];
        AGGC_EDGE(s0, w0); AGGC_EDGE(s1, w1); AGGC_EDGE(s2, w2); AGGC_EDGE(s3, w3);
        e += 4;
    }
    for (; e < e1; ++e) {
        int s0 = csr_src[e]; float w0 = csr_w[e];
        AGGC_EDGE(s0, w0);
    }

    if (FINAL) {
        int f2 = chunk * 16 + l;                        // float2 index in row
        float2 bb = ((const float2*)b2)[f2];
        float2 rr = ((const float2*)bres)[f2];
        float2 hres = ((float2*)xout)[(size_t)node * 64 + f2];
        float ox = fmaxf(ax + bb.x, 0.f) + hres.x + rr.x;
        float oy = fmaxf(ay + bb.y, 0.f) + hres.y + rr.y;
        ((float2*)xout)[(size_t)node * 64 + f2] = make_float2(ox, oy);
        ((unsigned int*)outb)[(size_t)node * 64 + f2] =
            (unsigned)f2bf(ox) | ((unsigned)f2bf(oy) << 16);
    } else {
        ((unsigned int*)outb)[((size_t)chunk * N + node) * 16 + l] =
            (unsigned)f2bf(ax) | ((unsigned)f2bf(ay) << 16);
    }
}

// ---- bf16 MFMA GEMM: C = A[M][K] @ Bt[Nn][K]^T -----------------------------
// BM=128 BN=256 BK=64, 512 threads = 8 waves (2 row x 4 col), swapped-operand
// 16x16x32 MFMA (lane owns 4 consecutive output cols -> packed stores).
// ACHUNK: A stored chunked [K/32][M][32]. PIPE: 2-phase reg-staged prefetch.
// MODE 1: Cb = bf16(relu(C+bias)) [M][Nn]
// MODE 2: col<128 -> Cb bf16 chunked [4][M][32]; col>=128 -> Cf f32 [M][128]
// MODE 3: Cf[row] += sum_col relu(C+bias)*w2 (atomic)

template <int MODE, int PIPE, int ACHUNK>
__global__ __launch_bounds__(512) void mgemm(const u16* __restrict__ A,
                                             const u16* __restrict__ Bt,
                                             int M, int Nn, int K,
                                             const float* __restrict__ bias,
                                             u16* __restrict__ Cb,
                                             float* __restrict__ Cf,
                                             const float* __restrict__ w2) {
    __shared__ u16 As[128][72];   // 18.4 KB (+8 pad, 16B-aligned rows)
    __shared__ u16 Bs[256][72];   // 36.9 KB
    const int t = threadIdx.x;
    const int bm = blockIdx.y * 128;
    const int bn = blockIdx.x * 256;
    const int w = t >> 6, lane = t & 63;
    const int wm = w >> 2, wn = w & 3;        // 2 x 4 wave grid
    const int l15 = lane & 15, lg = lane >> 4;
    const int srow = t >> 3, scol = (t & 7) * 8;   // staging: row += 64*i

    auto ald = [&](int grow, int col) -> us8 {
        if (grow >= M) return (us8)(u16)0;
        if (ACHUNK)
            return *(const us8*)(A + ((size_t)(col >> 5) * M + grow) * 32 + (col & 31));
        return *(const us8*)(A + (size_t)grow * K + col);
    };

    f32x4 acc[4][4];
#pragma unroll
    for (int i = 0; i < 4; ++i)
#pragma unroll
        for (int j = 0; j < 4; ++j) acc[i][j] = (f32x4)(0.0f);

    us8 ra[2], rb[4];
    if (PIPE) {   // prologue: stage K-tile 0 into registers
#pragma unroll
        for (int i = 0; i < 2; ++i) ra[i] = ald(bm + srow + 64 * i, scol);
#pragma unroll
        for (int i = 0; i < 4; ++i)
            rb[i] = *(const us8*)(Bt + (size_t)(bn + srow + 64 * i) * K + scol);
    }

    for (int kk = 0; kk < K; kk += 64) {
        if (PIPE) {
#pragma unroll
            for (int i = 0; i < 2; ++i) *(us8*)&As[srow + 64 * i][scol] = ra[i];
#pragma unroll
            for (int i = 0; i < 4; ++i) *(us8*)&Bs[srow + 64 * i][scol] = rb[i];
        } else {
#pragma unroll
            for (int i = 0; i < 2; ++i)
                *(us8*)&As[srow + 64 * i][scol] = ald(bm + srow + 64 * i, kk + scol);
#pragma unroll
            for (int i = 0; i < 4; ++i) {
                int row = srow + 64 * i;
                *(us8*)&Bs[row][scol] =
                    *(const us8*)(Bt + (size_t)(bn + row) * K + kk + scol);
            }
        }
        __syncthreads();

        if (PIPE && kk + 64 < K) {   // issue next tile's loads under the MFMAs
#pragma unroll
            for (int i = 0; i < 2; ++i) ra[i] = ald(bm + srow + 64 * i, kk + 64 + scol);
#pragma unroll
            for (int i = 0; i < 4; ++i)
                rb[i] = *(const us8*)(Bt + (size_t)(bn + srow + 64 * i) * K + kk + 64 + scol);
        }

#pragma unroll
        for (int ks = 0; ks < 2; ++ks) {
            const int ko = 32 * ks + lg * 8;
            bf16x8 bfr[4], afr[4];
#pragma unroll
            for (int fn = 0; fn < 4; ++fn)
                bfr[fn] = *(const bf16x8*)&Bs[64 * wn + 16 * fn + l15][ko];
#pragma unroll
            for (int fm = 0; fm < 4; ++fm)
                afr[fm] = *(const bf16x8*)&As[64 * wm + 16 * fm + l15][ko];
#pragma unroll
            for (int fm = 0; fm < 4; ++fm)
#pragma unroll
                for (int fn = 0; fn < 4; ++fn)
                    acc[fm][fn] = __builtin_amdgcn_mfma_f32_16x16x32_bf16(
                        bfr[fn], afr[fm], acc[fm][fn], 0, 0, 0);   // SWAPPED
        }
        __syncthreads();
    }

    // epilogue: lane owns rows m = bm+64*wm+16*fm+l15, cols n0 = bn+64*wn+16*fn+4*lg
    if (MODE == 3) {
        float4 bl4[4], wl4[4];
#pragma unroll
        for (int fn = 0; fn < 4; ++fn) {
            int c = bn + 64 * wn + 16 * fn + 4 * lg;
            bl4[fn] = *(const float4*)&bias[c];
            wl4[fn] = *(const float4*)&w2[c];
        }
#pragma unroll
        for (int fm = 0; fm < 4; ++fm) {
            float p = 0.f;
#pragma unroll
            for (int fn = 0; fn < 4; ++fn) {
                p += fmaxf(acc[fm][fn][0] + bl4[fn].x, 0.f) * wl4[fn].x;
                p += fmaxf(acc[fm][fn][1] + bl4[fn].y, 0.f) * wl4[fn].y;
                p += fmaxf(acc[fm][fn][2] + bl4[fn].z, 0.f) * wl4[fn].z;
                p += fmaxf(acc[fm][fn][3] + bl4[fn].w, 0.f) * wl4[fn].w;
            }
            p += __shfl_xor(p, 16);
            p += __shfl_xor(p, 32);
            int row = bm + 64 * wm + 16 * fm + l15;
            if (lane < 16 && row < M) atomicAdd(&Cf[row], p);
        }
        return;
    }

#pragma unroll
    for (int fm = 0; fm < 4; ++fm) {
        const int row = bm + 64 * wm + 16 * fm + l15;
        if (row >= M) continue;
#pragma unroll
        for (int fn = 0; fn < 4; ++fn) {
            const int col = bn + 64 * wn + 16 * fn + 4 * lg;
            f32x4 v = acc[fm][fn];
            if (MODE == 1) {
                float4 b4 = *(const float4*)&bias[col];
                float v0 = fmaxf(v[0] + b4.x, 0.f), v1 = fmaxf(v[1] + b4.y, 0.f);
                float v2 = fmaxf(v[2] + b4.z, 0.f), v3 = fmaxf(v[3] + b4.w, 0.f);
                uint2 o;
                o.x = (unsigned)f2bf(v0) | ((unsigned)f2bf(v1) << 16);
                o.y = (unsigned)f2bf(v2) | ((unsigned)f2bf(v3) << 16);
                *(uint2*)(Cb + (size_t)row * Nn + col) = o;
            } else {             // MODE 2: h2 -> chunked bf16, hres -> fp32
                if (col < 128) {
                    uint2 o;
                    o.x = (unsigned)f2bf(v[0]) | ((unsigned)f2bf(v[1]) << 16);
                    o.y = (unsigned)f2bf(v[2]) | ((unsigned)f2bf(v[3]) << 16);
                    *(uint2*)(Cb + ((size_t)(col >> 5) * M + row) * 32 + (col & 31)) = o;
                } else {
                    *(float4*)(Cf + (size_t)row * 128 + (col - 128)) =
                        make_float4(v[0], v[1], v[2], v[3]);
                }
            }
        }
    }
}

// ---------------------------------------------------------------------------

extern "C" void kernel_launch(void* const* d_in, const int* in_sizes, int n_in,
                              void* d_out, int out_size, void* d_ws, size_t ws_size,
                              hipStream_t stream) {
    const float* emb  = (const float*)d_in[0];
    const int*   eidx = (const int*)d_in[1];
    const float* W1   = (const float*)d_in[2];
    const float* b1   = (const float*)d_in[3];
    const float* W2   = (const float*)d_in[4];
    const float* b2   = (const float*)d_in[5];
    const float* Wres = (const float*)d_in[6];
    const float* bres = (const float*)d_in[7];
    const float* Wfc1 = (const float*)d_in[8];
    const float* bfc1 = (const float*)d_in[9];
    const float* Wfc2 = (const float*)d_in[10];
    const float* bfc2 = (const float*)d_in[11];

    const int N = in_sizes[0] / 128;
    const int E = in_sizes[1] / 2;
    const int* srcv = eidx;
    const int* dstv = eidx + E;

    float* out  = (float*)d_out;
    float* xout = out;                       // [N,128]
    float* Aout = out + (size_t)N * 128;     // [N]

    // ---- workspace layout ----
    char* p = (char*)d_ws;
    float* dinv  = (float*)p;            p += (size_t)N * 4;
    float* csr_w = (float*)p;            p += (size_t)E * 4;
    u16*  embb   = (u16*)p;              p += (size_t)N * 128 * 2;   // chunked [4][N][32]
    u16*  aggEb  = (u16*)p;              p += (size_t)N * 128 * 2;   // chunked [4][N][32]
    u16*  x1b    = (u16*)p;              p += (size_t)N * 512 * 2;   // flat [N][512]
    u16*  h2b    = (u16*)p;              p += (size_t)N * 128 * 2;   // chunked [4][N][32]
    u16*  xb     = (u16*)p;              p += (size_t)N * 128 * 2;   // flat [N][128]
    u16*  W1t    = (u16*)p;              p += (size_t)512 * 128 * 2;
    u16*  Wct    = (u16*)p;              p += (size_t)256 * 512 * 2;
    u16*  Wfc1t  = (u16*)p;              p += (size_t)256 * 128 * 2;
    int*  cnt     = (int*)p;             p += (size_t)N * 4;
    int*  excl    = (int*)p;             p += (size_t)N * 4;
    int*  rowptr  = (int*)p;             p += (size_t)(N + 1) * 4;
    int*  cursor  = (int*)p;             p += (size_t)N * 4;
    int*  bsum    = (int*)p;             p += 256 * 4;
    int*  csr_src = (int*)p;             p += (size_t)E * 4;

    const int T  = 256;
    const int nb = cdiv_ll(N, 256);      // <= 256 required by scanB

    // 1) fused setup (also zeroes cnt, inits Aout=bfc2)
    const long long setup_work = (long long)N * 32 + 512 * 128 + 256 * 512
                               + 256 * 128 + (long long)N + (long long)N;
    setup_kernel<<<cdiv_ll(setup_work, T), T, 0, stream>>>(
        emb, W1, W2, Wres, Wfc1, bfc2, embb, W1t, Wct, Wfc1t, cnt, Aout, N);

    // 2) CSR build + dinv (stream order guarantees cnt=0 before hist)
    hist_kernel<<<cdiv_ll(E, T), T, 0, stream>>>(dstv, cnt, E);
    scanA_kernel<<<nb, T, 0, stream>>>(cnt, excl, bsum, N);
    scanB_kernel<<<1, T, 0, stream>>>(bsum, nb);
    scanC_kernel<<<nb, T, 0, stream>>>(excl, bsum, cnt, rowptr, cursor, dinv, N, E);
    fill_kernel<<<cdiv_ll(E, T), T, 0, stream>>>(srcv, dstv, dinv, cursor, csr_src, csr_w, E);

    // 3) aggE = S @ emb  (chunked gather, chunked bf16 out)
    dim3 aggGrid(cdiv_ll(N, 16), 4);
    aggc_kernel<0><<<aggGrid, T, 0, stream>>>(
        embb, rowptr, csr_src, csr_w, dinv, nullptr, nullptr, nullptr, aggEb, N);

    // 4) x1 = relu(aggE @ W1 + b1) -> bf16 [N,512]   (A chunked, K=128 no pipe)
    mgemm<1, 0, 1><<<dim3(512 / 256, cdiv_ll(N, 128)), 512, 0, stream>>>(
        aggEb, W1t, N, 512, 128, b1, x1b, nullptr, nullptr);

    // 5) fused: h2 = x1@W2 (chunked bf16), hres = x1@Wres (fp32 -> xout)
    mgemm<2, 1, 0><<<dim3(1, cdiv_ll(N, 128)), 512, 0, stream>>>(
        x1b, Wct, N, 256, 512, nullptr, h2b, xout, nullptr);

    // 6) fused: x = relu(S@h2 + b2) + hres + bres -> xout (fp32) + xb (bf16)
    aggc_kernel<1><<<aggGrid, T, 0, stream>>>(
        h2b, rowptr, csr_src, csr_w, dinv, b2, bres, xout, xb, N);

    // 7) head: A += sum relu(xb@Wfc1t + bfc1) * Wfc2  (A pre-init to bfc2)
    mgemm<3, 0, 0><<<dim3(1, cdiv_ll(N, 128)), 512, 0, stream>>>(
        xb, Wfc1t, N, 256, 128, bfc1, nullptr, Aout, Wfc2);
}

// Round 9
// 178.309 us; speedup vs baseline: 1.1929x; 1.1929x over previous
//
#include <hip/hip_runtime.h>

// ---------------------------------------------------------------------------
// res_rand_GAE round 9: revert chunked gather (flat tables, r7 agg); FUSE
// GEMM1+GEMM2 into one kernel (x1 never leaves the block: 4 passes of
// 128-col x1 slice -> LDS -> GEMM2 k-accumulate), killing the 102 MB x1b
// round-trip; scanB folded into scanC. Outputs: x [N,128] ++ A [N,1] fp32.
// ---------------------------------------------------------------------------

typedef unsigned short u16;
typedef short bf16x8 __attribute__((ext_vector_type(8)));
typedef unsigned short us8 __attribute__((ext_vector_type(8)));
typedef float f32x4 __attribute__((ext_vector_type(4)));

static inline int cdiv_ll(long long a, long long b) { return (int)((a + b - 1) / b); }

__device__ inline float bf2f(u16 u) {
    union { unsigned int i; float f; } v; v.i = ((unsigned int)u) << 16; return v.f;
}
__device__ inline u16 f2bf(float x) {   // round-to-nearest-even
    union { float f; unsigned int i; } v; v.f = x;
    unsigned int r = v.i + 0x7fffu + ((v.i >> 16) & 1u);
    return (u16)(r >> 16);
}

// ---- fused setup: cnt=0, Aout=bfc2, emb->bf16, W1^T, Wcat^T, Wfc1^T --------

__global__ __launch_bounds__(256) void setup_kernel(const float* __restrict__ emb,
                                                    const float* __restrict__ W1,
                                                    const float* __restrict__ W2,
                                                    const float* __restrict__ Wres,
                                                    const float* __restrict__ Wfc1,
                                                    const float* __restrict__ bfc2,
                                                    u16* __restrict__ embb,
                                                    u16* __restrict__ W1t,
                                                    u16* __restrict__ Wct,
                                                    u16* __restrict__ Wfc1t,
                                                    int* __restrict__ cnt,
                                                    float* __restrict__ Aout,
                                                    int N) {
    long long r = (long long)blockIdx.x * 256 + threadIdx.x;
    const long long nf2b = (long long)N * 32;          // float4s of emb
    if (r < nf2b) {
        float4 v = ((const float4*)emb)[r];
        uint2 o;
        o.x = (unsigned)f2bf(v.x) | ((unsigned)f2bf(v.y) << 16);
        o.y = (unsigned)f2bf(v.z) | ((unsigned)f2bf(v.w) << 16);
        ((uint2*)embb)[r] = o;
        return;
    }
    r -= nf2b;
    if (r < 512 * 128) {                               // W1t[n*128+k] = W1[k*512+n]
        int n = (int)(r / 128), k = (int)(r % 128);
        W1t[r] = f2bf(W1[(size_t)k * 512 + n]);
        return;
    }
    r -= 512 * 128;
    if (r < 256 * 512) {                               // Wct[n*512+k]
        int n = (int)(r / 512), k = (int)(r % 512);
        float v = (n < 128) ? W2[(size_t)k * 128 + n] : Wres[(size_t)k * 128 + (n - 128)];
        Wct[r] = f2bf(v);
        return;
    }
    r -= 256 * 512;
    if (r < 256 * 128) {                               // Wfc1t[n*128+k]
        int n = (int)(r / 128), k = (int)(r % 128);
        Wfc1t[r] = f2bf(Wfc1[(size_t)k * 256 + n]);
        return;
    }
    r -= 256 * 128;
    if (r < N) { cnt[(int)r] = 0; return; }
    r -= N;
    if (r < N) Aout[(int)r] = bfc2[0];
}

// ---- CSR build -------------------------------------------------------------

__global__ __launch_bounds__(256) void hist_kernel(const int* __restrict__ dst,
                                                   int* __restrict__ cnt, int E) {
    int e = blockIdx.x * 256 + threadIdx.x;
    if (e < E) atomicAdd(&cnt[dst[e]], 1);
}

__global__ __launch_bounds__(256) void scanA_kernel(const int* __restrict__ cnt,
                                                    int* __restrict__ excl,
                                                    int* __restrict__ bsum, int N) {
    __shared__ int tmp[256];
    int i = blockIdx.x * 256 + threadIdx.x;
    int v = (i < N) ? cnt[i] : 0;
    tmp[threadIdx.x] = v;
    __syncthreads();
    for (int o = 1; o < 256; o <<= 1) {
        int t = (threadIdx.x >= (unsigned)o) ? tmp[threadIdx.x - o] : 0;
        __syncthreads();
        tmp[threadIdx.x] += t;
        __syncthreads();
    }
    if (i < N) excl[i] = tmp[threadIdx.x] - v;
    if (threadIdx.x == 255) bsum[blockIdx.x] = tmp[255];
}

// scanC2: block j reduces bsum[0..j-1] itself (drops the scanB launch)
__global__ __launch_bounds__(256) void scanC2_kernel(const int* __restrict__ excl,
                                                     const int* __restrict__ bsum,
                                                     const int* __restrict__ cnt,
                                                     int* __restrict__ rowptr,
                                                     int* __restrict__ cursor,
                                                     float* __restrict__ dinv,
                                                     int N, int E) {
    __shared__ int tmp[256];
    int t = threadIdx.x;
    tmp[t] = (t < (int)blockIdx.x) ? bsum[t] : 0;
    __syncthreads();
    for (int o = 128; o; o >>= 1) {
        if (t < o) tmp[t] += tmp[t + o];
        __syncthreads();
    }
    int pre = tmp[0];
    int i = blockIdx.x * 256 + t;
    if (i < N) {
        int r = excl[i] + pre;
        rowptr[i] = r;
        cursor[i] = r;
        dinv[i] = rsqrtf((float)cnt[i] + 2.0f);
    }
    if (i == 0) rowptr[N] = E;
}

__global__ __launch_bounds__(256) void fill_kernel(const int* __restrict__ src,
                                                   const int* __restrict__ dst,
                                                   const float* __restrict__ dinv,
                                                   int* __restrict__ cursor,
                                                   int* __restrict__ csr_src,
                                                   float* __restrict__ csr_w, int E) {
    int e = blockIdx.x * 256 + threadIdx.x;
    if (e >= E) return;
    int s = src[e], d = dst[e];
    int idx = atomicAdd(&cursor[d], 1);
    csr_src[idx] = s;
    csr_w[idx] = dinv[s] * dinv[d];
}

// ---- wave-per-node CSR aggregation over flat bf16 table [N][128] -----------

#define AGG_EDGE(SR, WR)                                                       \
    {                                                                          \
        unsigned int vv = hp[(size_t)(SR) * 64 + lane];                        \
        ax = fmaf(bf2f((u16)vv), (WR), ax);                                    \
        ay = fmaf(bf2f((u16)(vv >> 16)), (WR), ay);                            \
    }

__device__ inline void agg_row(const unsigned int* __restrict__ hp,
                               const int* __restrict__ rowptr,
                               const int* __restrict__ csr_src,
                               const float* __restrict__ csr_w,
                               const float* __restrict__ dinv,
                               int wid, int lane, float& ax, float& ay) {
    float dv = dinv[wid];
    unsigned int hv = hp[(size_t)wid * 64 + lane];
    float c0 = 2.0f * dv * dv;
    ax = bf2f((u16)hv) * c0;
    ay = bf2f((u16)(hv >> 16)) * c0;
    int e = rowptr[wid], e1 = rowptr[wid + 1];
    for (; e + 7 < e1; e += 8) {
        int s0 = csr_src[e + 0], s1 = csr_src[e + 1], s2 = csr_src[e + 2], s3 = csr_src[e + 3];
        int s4 = csr_src[e + 4], s5 = csr_src[e + 5], s6 = csr_src[e + 6], s7 = csr_src[e + 7];
        float w0 = csr_w[e + 0], w1 = csr_w[e + 1], w2 = csr_w[e + 2], w3 = csr_w[e + 3];
        float w4 = csr_w[e + 4], w5 = csr_w[e + 5], w6 = csr_w[e + 6], w7 = csr_w[e + 7];
        AGG_EDGE(s0, w0); AGG_EDGE(s1, w1); AGG_EDGE(s2, w2); AGG_EDGE(s3, w3);
        AGG_EDGE(s4, w4); AGG_EDGE(s5, w5); AGG_EDGE(s6, w6); AGG_EDGE(s7, w7);
    }
    if (e + 3 < e1) {
        int s0 = csr_src[e + 0], s1 = csr_src[e + 1], s2 = csr_src[e + 2], s3 = csr_src[e + 3];
        float w0 = csr_w[e + 0], w1 = csr_w[e + 1], w2 = csr_w[e + 2], w3 = csr_w[e + 3];
        AGG_EDGE(s0, w0); AGG_EDGE(s1, w1); AGG_EDGE(s2, w2); AGG_EDGE(s3, w3);
        e += 4;
    }
    for (; e < e1; ++e) {
        int s0 = csr_src[e]; float w0 = csr_w[e];
        AGG_EDGE(s0, w0);
    }
}

__global__ __launch_bounds__(256) void aggb_kernel(const u16* __restrict__ hb,
                                                   const int* __restrict__ rowptr,
                                                   const int* __restrict__ csr_src,
                                                   const float* __restrict__ csr_w,
                                                   const float* __restrict__ dinv,
                                                   u16* __restrict__ out, int N) {
    int wid  = (blockIdx.x * blockDim.x + threadIdx.x) >> 6;
    int lane = threadIdx.x & 63;
    if (wid >= N) return;
    float ax, ay;
    agg_row((const unsigned int*)hb, rowptr, csr_src, csr_w, dinv, wid, lane, ax, ay);
    ((unsigned int*)out)[(size_t)wid * 64 + lane] =
        (unsigned)f2bf(ax) | ((unsigned)f2bf(ay) << 16);
}

// fused: x = relu(agg(h2) + b2) + hres + bres -> xout fp32 AND xb bf16
__global__ __launch_bounds__(256) void aggfin_kernel(const u16* __restrict__ hb,
                                                     const int* __restrict__ rowptr,
                                                     const int* __restrict__ csr_src,
                                                     const float* __restrict__ csr_w,
                                                     const float* __restrict__ dinv,
                                                     const float* __restrict__ b2,
                                                     const float* __restrict__ bres,
                                                     float* __restrict__ xout,
                                                     u16* __restrict__ xb, int N) {
    int wid  = (blockIdx.x * blockDim.x + threadIdx.x) >> 6;
    int lane = threadIdx.x & 63;
    if (wid >= N) return;
    float ax, ay;
    agg_row((const unsigned int*)hb, rowptr, csr_src, csr_w, dinv, wid, lane, ax, ay);
    float2 bb = ((const float2*)b2)[lane];
    float2 rr = ((const float2*)bres)[lane];
    float2 hres = ((float2*)xout)[(size_t)wid * 64 + lane];
    float ox = fmaxf(ax + bb.x, 0.f) + hres.x + rr.x;
    float oy = fmaxf(ay + bb.y, 0.f) + hres.y + rr.y;
    ((float2*)xout)[(size_t)wid * 64 + lane] = make_float2(ox, oy);
    ((unsigned int*)xb)[(size_t)wid * 64 + lane] =
        (unsigned)f2bf(ox) | ((unsigned)f2bf(oy) << 16);
}

// ---- fused GEMM1+GEMM2: per 128-row block -----------------------------------
// x1 = relu(aggE@W1 + b1) computed in 4 passes of 128 cols; each pass's slice
// goes to LDS and is immediately consumed as GEMM2's k-slice:
//   h2  = x1 @ W2   -> h2b bf16 [M][128]
//   hres= x1 @ Wres -> xout f32 [M][128]
// 512 threads = 8 waves (2x4). Swapped-operand MFMA throughout.
// Dynamic LDS: Ag[128][136] | Ws[256][136] | X1s[128][136]  (139,264 B)

__global__ __launch_bounds__(512) void mgemm12(const u16* __restrict__ aggE,
                                               const u16* __restrict__ W1t,
                                               const u16* __restrict__ Wct,
                                               const float* __restrict__ b1,
                                               int M,
                                               u16* __restrict__ h2b,
                                               float* __restrict__ xout) {
    extern __shared__ u16 smem[];
    u16* Ag  = smem;                    // [128][136]
    u16* Ws  = Ag + 128 * 136;          // [256][136]
    u16* X1s = Ws + 256 * 136;          // [128][136]
    const int LD = 136;

    const int t = threadIdx.x;
    const int bm = blockIdx.x * 128;
    const int w = t >> 6, lane = t & 63;
    const int wm = w >> 2, wn = w & 3;        // 2 x 4 wave grid
    const int l15 = lane & 15, lg = lane >> 4;

    // stage aggE tile [128][128] (zero-pad rows >= M)
#pragma unroll
    for (int i = 0; i < 4; ++i) {
        int c = t + 512 * i;
        int row = c >> 4, cs = (c & 15) * 8;
        us8 v = (us8)(u16)0;
        if (bm + row < M) v = *(const us8*)(aggE + (size_t)(bm + row) * 128 + cs);
        *(us8*)&Ag[row * LD + cs] = v;
    }

    f32x4 acc2[4][4];
#pragma unroll
    for (int i = 0; i < 4; ++i)
#pragma unroll
        for (int j = 0; j < 4; ++j) acc2[i][j] = (f32x4)(0.0f);

    for (int p = 0; p < 4; ++p) {
        __syncthreads();   // prior pass's Ws/X1s reads done (also Ag stores on p=0)
        // stage Ws <- W1t rows [128p .. 128p+128), K=128
#pragma unroll
        for (int i = 0; i < 4; ++i) {
            int c = t + 512 * i;
            int row = c >> 4, cs = (c & 15) * 8;
            *(us8*)&Ws[row * LD + cs] =
                *(const us8*)(W1t + (size_t)(128 * p + row) * 128 + cs);
        }
        __syncthreads();

        // GEMM1: x1 slice [128 rows][128 cols], K = 128
        f32x4 acc1[4][2];
#pragma unroll
        for (int i = 0; i < 4; ++i)
#pragma unroll
            for (int j = 0; j < 2; ++j) acc1[i][j] = (f32x4)(0.0f);
#pragma unroll
        for (int ks = 0; ks < 4; ++ks) {
            const int ko = 32 * ks + lg * 8;
            bf16x8 wfr[2], afr[4];
#pragma unroll
            for (int fn = 0; fn < 2; ++fn)
                wfr[fn] = *(const bf16x8*)&Ws[(32 * wn + 16 * fn + l15) * LD + ko];
#pragma unroll
            for (int fm = 0; fm < 4; ++fm)
                afr[fm] = *(const bf16x8*)&Ag[(64 * wm + 16 * fm + l15) * LD + ko];
#pragma unroll
            for (int fm = 0; fm < 4; ++fm)
#pragma unroll
                for (int fn = 0; fn < 2; ++fn)
                    acc1[fm][fn] = __builtin_amdgcn_mfma_f32_16x16x32_bf16(
                        wfr[fn], afr[fm], acc1[fm][fn], 0, 0, 0);
        }
        __syncthreads();   // Ws reads done

        // write x1 slice (bias+relu, bf16) to X1s; stage Ws <- Wct k-slice
#pragma unroll
        for (int fm = 0; fm < 4; ++fm) {
#pragma unroll
            for (int fn = 0; fn < 2; ++fn) {
                int col1 = 32 * wn + 16 * fn + 4 * lg;         // 0..124
                float4 b4 = *(const float4*)&b1[128 * p + col1];
                f32x4 v = acc1[fm][fn];
                float v0 = fmaxf(v[0] + b4.x, 0.f), v1 = fmaxf(v[1] + b4.y, 0.f);
                float v2 = fmaxf(v[2] + b4.z, 0.f), v3 = fmaxf(v[3] + b4.w, 0.f);
                uint2 o;
                o.x = (unsigned)f2bf(v0) | ((unsigned)f2bf(v1) << 16);
                o.y = (unsigned)f2bf(v2) | ((unsigned)f2bf(v3) << 16);
                *(uint2*)&X1s[(64 * wm + 16 * fm + l15) * LD + col1] = o;
            }
        }
#pragma unroll
        for (int i = 0; i < 8; ++i) {
            int c = t + 512 * i;
            int row = c >> 4, cs = (c & 15) * 8;   // row 0..255, cs 0..120
            *(us8*)&Ws[row * LD + cs] =
                *(const us8*)(Wct + (size_t)row * 512 + 128 * p + cs);
        }
        __syncthreads();

        // GEMM2 accumulate: acc2 += Wct-slice x x1-slice (k = 128)
#pragma unroll
        for (int ks = 0; ks < 4; ++ks) {
            const int ko = 32 * ks + lg * 8;
            bf16x8 wfr[4], xfr[4];
#pragma unroll
            for (int fn = 0; fn < 4; ++fn)
                wfr[fn] = *(const bf16x8*)&Ws[(64 * wn + 16 * fn + l15) * LD + ko];
#pragma unroll
            for (int fm = 0; fm < 4; ++fm)
                xfr[fm] = *(const bf16x8*)&X1s[(64 * wm + 16 * fm + l15) * LD + ko];
#pragma unroll
            for (int fm = 0; fm < 4; ++fm)
#pragma unroll
                for (int fn = 0; fn < 4; ++fn)
                    acc2[fm][fn] = __builtin_amdgcn_mfma_f32_16x16x32_bf16(
                        wfr[fn], xfr[fm], acc2[fm][fn], 0, 0, 0);
        }
    }

    // epilogue: row = bm+64wm+16fm+l15; col = 64wn+16fn+4lg (+r)
#pragma unroll
    for (int fm = 0; fm < 4; ++fm) {
        const int row = bm + 64 * wm + 16 * fm + l15;
        if (row >= M) continue;
#pragma unroll
        for (int fn = 0; fn < 4; ++fn) {
            const int col = 64 * wn + 16 * fn + 4 * lg;
            f32x4 v = acc2[fm][fn];
            if (col < 128) {                      // h2 -> bf16
                uint2 o;
                o.x = (unsigned)f2bf(v[0]) | ((unsigned)f2bf(v[1]) << 16);
                o.y = (unsigned)f2bf(v[2]) | ((unsigned)f2bf(v[3]) << 16);
                *(uint2*)(h2b + (size_t)row * 128 + col) = o;
            } else {                              // hres -> fp32
                *(float4*)(xout + (size_t)row * 128 + (col - 128)) =
                    make_float4(v[0], v[1], v[2], v[3]);
            }
        }
    }
}

// ---- head GEMM: A[row] += sum_col relu((xb@Wfc1t)[row][col]+bfc1)*Wfc2 -----
// BM=128, BN=256 (all hidden), K=128; swapped-operand MFMA; atomic row-sum.

__global__ __launch_bounds__(512) void head_gemm(const u16* __restrict__ A,
                                                 const u16* __restrict__ Bt,
                                                 int M,
                                                 const float* __restrict__ bias,
                                                 const float* __restrict__ w2,
                                                 float* __restrict__ Cf) {
    __shared__ u16 As[128][72];
    __shared__ u16 Bs[256][72];
    const int t = threadIdx.x;
    const int bm = blockIdx.x * 128;
    const int w = t >> 6, lane = t & 63;
    const int wm = w >> 2, wn = w & 3;
    const int l15 = lane & 15, lg = lane >> 4;
    const int srow = t >> 3, scol = (t & 7) * 8;
    const int K = 128;

    f32x4 acc[4][4];
#pragma unroll
    for (int i = 0; i < 4; ++i)
#pragma unroll
        for (int j = 0; j < 4; ++j) acc[i][j] = (f32x4)(0.0f);

    for (int kk = 0; kk < K; kk += 64) {
#pragma unroll
        for (int i = 0; i < 2; ++i) {
            int row = srow + 64 * i;
            us8 v = (us8)(u16)0;
            if (bm + row < M)
                v = *(const us8*)(A + (size_t)(bm + row) * K + kk + scol);
            *(us8*)&As[row][scol] = v;
        }
#pragma unroll
        for (int i = 0; i < 4; ++i) {
            int row = srow + 64 * i;
            *(us8*)&Bs[row][scol] =
                *(const us8*)(Bt + (size_t)row * K + kk + scol);
        }
        __syncthreads();
#pragma unroll
        for (int ks = 0; ks < 2; ++ks) {
            const int ko = 32 * ks + lg * 8;
            bf16x8 bfr[4], afr[4];
#pragma unroll
            for (int fn = 0; fn < 4; ++fn)
                bfr[fn] = *(const bf16x8*)&Bs[64 * wn + 16 * fn + l15][ko];
#pragma unroll
            for (int fm = 0; fm < 4; ++fm)
                afr[fm] = *(const bf16x8*)&As[64 * wm + 16 * fm + l15][ko];
#pragma unroll
            for (int fm = 0; fm < 4; ++fm)
#pragma unroll
                for (int fn = 0; fn < 4; ++fn)
                    acc[fm][fn] = __builtin_amdgcn_mfma_f32_16x16x32_bf16(
                        bfr[fn], afr[fm], acc[fm][fn], 0, 0, 0);
        }
        __syncthreads();
    }

    float4 bl4[4], wl4[4];
#pragma unroll
    for (int fn = 0; fn < 4; ++fn) {
        int c = 64 * wn + 16 * fn + 4 * lg;
        bl4[fn] = *(const float4*)&bias[c];
        wl4[fn] = *(const float4*)&w2[c];
    }
#pragma unroll
    for (int fm = 0; fm < 4; ++fm) {
        float p = 0.f;
#pragma unroll
        for (int fn = 0; fn < 4; ++fn) {
            p += fmaxf(acc[fm][fn][0] + bl4[fn].x, 0.f) * wl4[fn].x;
            p += fmaxf(acc[fm][fn][1] + bl4[fn].y, 0.f) * wl4[fn].y;
            p += fmaxf(acc[fm][fn][2] + bl4[fn].z, 0.f) * wl4[fn].z;
            p += fmaxf(acc[fm][fn][3] + bl4[fn].w, 0.f) * wl4[fn].w;
        }
        p += __shfl_xor(p, 16);
        p += __shfl_xor(p, 32);
        int row = bm + 64 * wm + 16 * fm + l15;
        if (lane < 16 && row < M) atomicAdd(&Cf[row], p);
    }
}

// ---------------------------------------------------------------------------

extern "C" void kernel_launch(void* const* d_in, const int* in_sizes, int n_in,
                              void* d_out, int out_size, void* d_ws, size_t ws_size,
                              hipStream_t stream) {
    const float* emb  = (const float*)d_in[0];
    const int*   eidx = (const int*)d_in[1];
    const float* W1   = (const float*)d_in[2];
    const float* b1   = (const float*)d_in[3];
    const float* W2   = (const float*)d_in[4];
    const float* b2   = (const float*)d_in[5];
    const float* Wres = (const float*)d_in[6];
    const float* bres = (const float*)d_in[7];
    const float* Wfc1 = (const float*)d_in[8];
    const float* bfc1 = (const float*)d_in[9];
    const float* Wfc2 = (const float*)d_in[10];
    const float* bfc2 = (const float*)d_in[11];

    const int N = in_sizes[0] / 128;
    const int E = in_sizes[1] / 2;
    const int* srcv = eidx;
    const int* dstv = eidx + E;

    float* out  = (float*)d_out;
    float* xout = out;                       // [N,128]
    float* Aout = out + (size_t)N * 128;     // [N]

    // ---- workspace layout ----
    char* p = (char*)d_ws;
    float* dinv  = (float*)p;            p += (size_t)N * 4;
    float* csr_w = (float*)p;            p += (size_t)E * 4;
    u16*  embb   = (u16*)p;              p += (size_t)N * 128 * 2;   // flat [N][128]
    u16*  aggEb  = (u16*)p;              p += (size_t)N * 128 * 2;   // flat [N][128]
    u16*  h2b    = (u16*)p;              p += (size_t)N * 128 * 2;   // flat [N][128]
    u16*  xb     = (u16*)p;              p += (size_t)N * 128 * 2;   // flat [N][128]
    u16*  W1t    = (u16*)p;              p += (size_t)512 * 128 * 2;
    u16*  Wct    = (u16*)p;              p += (size_t)256 * 512 * 2;
    u16*  Wfc1t  = (u16*)p;              p += (size_t)256 * 128 * 2;
    int*  cnt     = (int*)p;             p += (size_t)N * 4;
    int*  excl    = (int*)p;             p += (size_t)N * 4;
    int*  rowptr  = (int*)p;             p += (size_t)(N + 1) * 4;
    int*  cursor  = (int*)p;             p += (size_t)N * 4;
    int*  bsum    = (int*)p;             p += 256 * 4;
    int*  csr_src = (int*)p;             p += (size_t)E * 4;

    const int T  = 256;
    const int nb = cdiv_ll(N, 256);      // <= 256 required by scanC2

    // 1) fused setup (also zeroes cnt, inits Aout=bfc2)
    const long long setup_work = (long long)N * 32 + 512 * 128 + 256 * 512
                               + 256 * 128 + (long long)N + (long long)N;
    setup_kernel<<<cdiv_ll(setup_work, T), T, 0, stream>>>(
        emb, W1, W2, Wres, Wfc1, bfc2, embb, W1t, Wct, Wfc1t, cnt, Aout, N);

    // 2) CSR build + dinv
    hist_kernel<<<cdiv_ll(E, T), T, 0, stream>>>(dstv, cnt, E);
    scanA_kernel<<<nb, T, 0, stream>>>(cnt, excl, bsum, N);
    scanC2_kernel<<<nb, T, 0, stream>>>(excl, bsum, cnt, rowptr, cursor, dinv, N, E);
    fill_kernel<<<cdiv_ll(E, T), T, 0, stream>>>(srcv, dstv, dinv, cursor, csr_src, csr_w, E);

    // 3) aggE = S @ emb  (flat bf16)
    aggb_kernel<<<cdiv_ll((long long)N * 64, T), T, 0, stream>>>(
        embb, rowptr, csr_src, csr_w, dinv, aggEb, N);

    // 4) fused GEMM1+GEMM2: h2 = relu(aggE@W1+b1)@W2, hres = relu(...)@Wres
    const size_t lds12 = (size_t)(128 * 136 + 256 * 136 + 128 * 136) * sizeof(u16);
    mgemm12<<<cdiv_ll(N, 128), 512, lds12, stream>>>(
        aggEb, W1t, Wct, b1, N, h2b, xout);

    // 5) fused: x = relu(S@h2 + b2) + hres + bres -> xout (fp32) + xb (bf16)
    aggfin_kernel<<<cdiv_ll((long long)N * 64, T), T, 0, stream>>>(
        h2b, rowptr, csr_src, csr_w, dinv, b2, bres, xout, xb, N);

    // 6) head: A += sum relu(xb@Wfc1t + bfc1) * Wfc2  (A pre-init to bfc2)
    head_gemm<<<cdiv_ll(N, 128), 512, 0, stream>>>(
        xb, Wfc1t, N, bfc1, Wfc2, Aout);
}

// Round 10
// 176.866 us; speedup vs baseline: 1.2027x; 1.0082x over previous
//
#include <hip/hip_runtime.h>

// ---------------------------------------------------------------------------
// res_rand_GAE round 10: r9 + register-prefetched weight staging in mgemm12
// (Wct slice loads issued before GEMM1's MFMAs, next W1t slice before GEMM2's
// -> global-load latency hidden under compute). Outputs: x [N,128] ++ A [N].
// ---------------------------------------------------------------------------

typedef unsigned short u16;
typedef short bf16x8 __attribute__((ext_vector_type(8)));
typedef unsigned short us8 __attribute__((ext_vector_type(8)));
typedef float f32x4 __attribute__((ext_vector_type(4)));

static inline int cdiv_ll(long long a, long long b) { return (int)((a + b - 1) / b); }

__device__ inline float bf2f(u16 u) {
    union { unsigned int i; float f; } v; v.i = ((unsigned int)u) << 16; return v.f;
}
__device__ inline u16 f2bf(float x) {   // round-to-nearest-even
    union { float f; unsigned int i; } v; v.f = x;
    unsigned int r = v.i + 0x7fffu + ((v.i >> 16) & 1u);
    return (u16)(r >> 16);
}

// ---- fused setup: cnt=0, Aout=bfc2, emb->bf16, W1^T, Wcat^T, Wfc1^T --------

__global__ __launch_bounds__(256) void setup_kernel(const float* __restrict__ emb,
                                                    const float* __restrict__ W1,
                                                    const float* __restrict__ W2,
                                                    const float* __restrict__ Wres,
                                                    const float* __restrict__ Wfc1,
                                                    const float* __restrict__ bfc2,
                                                    u16* __restrict__ embb,
                                                    u16* __restrict__ W1t,
                                                    u16* __restrict__ Wct,
                                                    u16* __restrict__ Wfc1t,
                                                    int* __restrict__ cnt,
                                                    float* __restrict__ Aout,
                                                    int N) {
    long long r = (long long)blockIdx.x * 256 + threadIdx.x;
    const long long nf2b = (long long)N * 32;          // float4s of emb
    if (r < nf2b) {
        float4 v = ((const float4*)emb)[r];
        uint2 o;
        o.x = (unsigned)f2bf(v.x) | ((unsigned)f2bf(v.y) << 16);
        o.y = (unsigned)f2bf(v.z) | ((unsigned)f2bf(v.w) << 16);
        ((uint2*)embb)[r] = o;
        return;
    }
    r -= nf2b;
    if (r < 512 * 128) {                               // W1t[n*128+k] = W1[k*512+n]
        int n = (int)(r / 128), k = (int)(r % 128);
        W1t[r] = f2bf(W1[(size_t)k * 512 + n]);
        return;
    }
    r -= 512 * 128;
    if (r < 256 * 512) {                               // Wct[n*512+k]
        int n = (int)(r / 512), k = (int)(r % 512);
        float v = (n < 128) ? W2[(size_t)k * 128 + n] : Wres[(size_t)k * 128 + (n - 128)];
        Wct[r] = f2bf(v);
        return;
    }
    r -= 256 * 512;
    if (r < 256 * 128) {                               // Wfc1t[n*128+k]
        int n = (int)(r / 128), k = (int)(r % 128);
        Wfc1t[r] = f2bf(Wfc1[(size_t)k * 256 + n]);
        return;
    }
    r -= 256 * 128;
    if (r < N) { cnt[(int)r] = 0; return; }
    r -= N;
    if (r < N) Aout[(int)r] = bfc2[0];
}

// ---- CSR build -------------------------------------------------------------

__global__ __launch_bounds__(256) void hist_kernel(const int* __restrict__ dst,
                                                   int* __restrict__ cnt, int E) {
    int e = blockIdx.x * 256 + threadIdx.x;
    if (e < E) atomicAdd(&cnt[dst[e]], 1);
}

__global__ __launch_bounds__(256) void scanA_kernel(const int* __restrict__ cnt,
                                                    int* __restrict__ excl,
                                                    int* __restrict__ bsum, int N) {
    __shared__ int tmp[256];
    int i = blockIdx.x * 256 + threadIdx.x;
    int v = (i < N) ? cnt[i] : 0;
    tmp[threadIdx.x] = v;
    __syncthreads();
    for (int o = 1; o < 256; o <<= 1) {
        int t = (threadIdx.x >= (unsigned)o) ? tmp[threadIdx.x - o] : 0;
        __syncthreads();
        tmp[threadIdx.x] += t;
        __syncthreads();
    }
    if (i < N) excl[i] = tmp[threadIdx.x] - v;
    if (threadIdx.x == 255) bsum[blockIdx.x] = tmp[255];
}

// scanC2: block j reduces bsum[0..j-1] itself (no scanB launch)
__global__ __launch_bounds__(256) void scanC2_kernel(const int* __restrict__ excl,
                                                     const int* __restrict__ bsum,
                                                     const int* __restrict__ cnt,
                                                     int* __restrict__ rowptr,
                                                     int* __restrict__ cursor,
                                                     float* __restrict__ dinv,
                                                     int N, int E) {
    __shared__ int tmp[256];
    int t = threadIdx.x;
    tmp[t] = (t < (int)blockIdx.x) ? bsum[t] : 0;
    __syncthreads();
    for (int o = 128; o; o >>= 1) {
        if (t < o) tmp[t] += tmp[t + o];
        __syncthreads();
    }
    int pre = tmp[0];
    int i = blockIdx.x * 256 + t;
    if (i < N) {
        int r = excl[i] + pre;
        rowptr[i] = r;
        cursor[i] = r;
        dinv[i] = rsqrtf((float)cnt[i] + 2.0f);
    }
    if (i == 0) rowptr[N] = E;
}

__global__ __launch_bounds__(256) void fill_kernel(const int* __restrict__ src,
                                                   const int* __restrict__ dst,
                                                   const float* __restrict__ dinv,
                                                   int* __restrict__ cursor,
                                                   int* __restrict__ csr_src,
                                                   float* __restrict__ csr_w, int E) {
    int e = blockIdx.x * 256 + threadIdx.x;
    if (e >= E) return;
    int s = src[e], d = dst[e];
    int idx = atomicAdd(&cursor[d], 1);
    csr_src[idx] = s;
    csr_w[idx] = dinv[s] * dinv[d];
}

// ---- wave-per-node CSR aggregation over flat bf16 table [N][128] -----------

#define AGG_EDGE(SR, WR)                                                       \
    {                                                                          \
        unsigned int vv = hp[(size_t)(SR) * 64 + lane];                        \
        ax = fmaf(bf2f((u16)vv), (WR), ax);                                    \
        ay = fmaf(bf2f((u16)(vv >> 16)), (WR), ay);                            \
    }

__device__ inline void agg_row(const unsigned int* __restrict__ hp,
                               const int* __restrict__ rowptr,
                               const int* __restrict__ csr_src,
                               const float* __restrict__ csr_w,
                               const float* __restrict__ dinv,
                               int wid, int lane, float& ax, float& ay) {
    float dv = dinv[wid];
    unsigned int hv = hp[(size_t)wid * 64 + lane];
    float c0 = 2.0f * dv * dv;
    ax = bf2f((u16)hv) * c0;
    ay = bf2f((u16)(hv >> 16)) * c0;
    int e = rowptr[wid], e1 = rowptr[wid + 1];
    for (; e + 7 < e1; e += 8) {
        int s0 = csr_src[e + 0], s1 = csr_src[e + 1], s2 = csr_src[e + 2], s3 = csr_src[e + 3];
        int s4 = csr_src[e + 4], s5 = csr_src[e + 5], s6 = csr_src[e + 6], s7 = csr_src[e + 7];
        float w0 = csr_w[e + 0], w1 = csr_w[e + 1], w2 = csr_w[e + 2], w3 = csr_w[e + 3];
        float w4 = csr_w[e + 4], w5 = csr_w[e + 5], w6 = csr_w[e + 6], w7 = csr_w[e + 7];
        AGG_EDGE(s0, w0); AGG_EDGE(s1, w1); AGG_EDGE(s2, w2); AGG_EDGE(s3, w3);
        AGG_EDGE(s4, w4); AGG_EDGE(s5, w5); AGG_EDGE(s6, w6); AGG_EDGE(s7, w7);
    }
    if (e + 3 < e1) {
        int s0 = csr_src[e + 0], s1 = csr_src[e + 1], s2 = csr_src[e + 2], s3 = csr_src[e + 3];
        float w0 = csr_w[e + 0], w1 = csr_w[e + 1], w2 = csr_w[e + 2], w3 = csr_w[e + 3];
        AGG_EDGE(s0, w0); AGG_EDGE(s1, w1); AGG_EDGE(s2, w2); AGG_EDGE(s3, w3);
        e += 4;
    }
    for (; e < e1; ++e) {
        int s0 = csr_src[e]; float w0 = csr_w[e];
        AGG_EDGE(s0, w0);
    }
}

__global__ __launch_bounds__(256) void aggb_kernel(const u16* __restrict__ hb,
                                                   const int* __restrict__ rowptr,
                                                   const int* __restrict__ csr_src,
                                                   const float* __restrict__ csr_w,
                                                   const float* __restrict__ dinv,
                                                   u16* __restrict__ out, int N) {
    int wid  = (blockIdx.x * blockDim.x + threadIdx.x) >> 6;
    int lane = threadIdx.x & 63;
    if (wid >= N) return;
    float ax, ay;
    agg_row((const unsigned int*)hb, rowptr, csr_src, csr_w, dinv, wid, lane, ax, ay);
    ((unsigned int*)out)[(size_t)wid * 64 + lane] =
        (unsigned)f2bf(ax) | ((unsigned)f2bf(ay) << 16);
}

// fused: x = relu(agg(h2) + b2) + hres + bres -> xout fp32 AND xb bf16
__global__ __launch_bounds__(256) void aggfin_kernel(const u16* __restrict__ hb,
                                                     const int* __restrict__ rowptr,
                                                     const int* __restrict__ csr_src,
                                                     const float* __restrict__ csr_w,
                                                     const float* __restrict__ dinv,
                                                     const float* __restrict__ b2,
                                                     const float* __restrict__ bres,
                                                     float* __restrict__ xout,
                                                     u16* __restrict__ xb, int N) {
    int wid  = (blockIdx.x * blockDim.x + threadIdx.x) >> 6;
    int lane = threadIdx.x & 63;
    if (wid >= N) return;
    float ax, ay;
    agg_row((const unsigned int*)hb, rowptr, csr_src, csr_w, dinv, wid, lane, ax, ay);
    float2 bb = ((const float2*)b2)[lane];
    float2 rr = ((const float2*)bres)[lane];
    float2 hres = ((float2*)xout)[(size_t)wid * 64 + lane];
    float ox = fmaxf(ax + bb.x, 0.f) + hres.x + rr.x;
    float oy = fmaxf(ay + bb.y, 0.f) + hres.y + rr.y;
    ((float2*)xout)[(size_t)wid * 64 + lane] = make_float2(ox, oy);
    ((unsigned int*)xb)[(size_t)wid * 64 + lane] =
        (unsigned)f2bf(ox) | ((unsigned)f2bf(oy) << 16);
}

// ---- fused GEMM1+GEMM2 with register-prefetched weight staging --------------
// Per 128-row block: x1 = relu(aggE@W1 + b1) in 4 passes of 128 cols; each
// pass's slice -> LDS -> GEMM2 k-accumulate (h2 = x1@W2 bf16; hres = x1@Wres
// fp32). Wct slice loads issue before GEMM1's MFMAs; next W1t slice loads
// issue before GEMM2's MFMAs -> global latency hidden under compute.
// 512 threads = 8 waves (2x4). Swapped-operand MFMA.
// Dynamic LDS: Ag[128][136] | Ws[256][136] | X1s[128][136]  (139,264 B)

__global__ __launch_bounds__(512) void mgemm12(const u16* __restrict__ aggE,
                                               const u16* __restrict__ W1t,
                                               const u16* __restrict__ Wct,
                                               const float* __restrict__ b1,
                                               int M,
                                               u16* __restrict__ h2b,
                                               float* __restrict__ xout) {
    extern __shared__ u16 smem[];
    u16* Ag  = smem;                    // [128][136]
    u16* Ws  = Ag + 128 * 136;          // [256][136]
    u16* X1s = Ws + 256 * 136;          // [128][136]
    const int LD = 136;

    const int t = threadIdx.x;
    const int bm = blockIdx.x * 128;
    const int w = t >> 6, lane = t & 63;
    const int wm = w >> 2, wn = w & 3;        // 2 x 4 wave grid
    const int l15 = lane & 15, lg = lane >> 4;
    const int srow = t >> 4, scol = (t & 15) * 8;   // staging coords (row 0..31 +32*i)

    // stage aggE tile [128][128] (zero-pad rows >= M)
#pragma unroll
    for (int i = 0; i < 4; ++i) {
        int row = srow + 32 * i;
        us8 v = (us8)(u16)0;
        if (bm + row < M) v = *(const us8*)(aggE + (size_t)(bm + row) * 128 + scol);
        *(us8*)&Ag[row * LD + scol] = v;
    }

    f32x4 acc2[4][4];
#pragma unroll
    for (int i = 0; i < 4; ++i)
#pragma unroll
        for (int j = 0; j < 4; ++j) acc2[i][j] = (f32x4)(0.0f);

    us8 rw1[4], rwc[8];
    // prologue: preload pass-0 W1t slice into registers
#pragma unroll
    for (int i = 0; i < 4; ++i)
        rw1[i] = *(const us8*)(W1t + (size_t)(srow + 32 * i) * 128 + scol);

    for (int p = 0; p < 4; ++p) {
        __syncthreads();   // Ws free (prior GEMM2 done); Ag stores visible (p=0)
        // Ws <- rw1 (W1t slice, 128 rows)
#pragma unroll
        for (int i = 0; i < 4; ++i)
            *(us8*)&Ws[(srow + 32 * i) * LD + scol] = rw1[i];
        __syncthreads();

        // issue this pass's Wct slice loads (land during GEMM1)
#pragma unroll
        for (int i = 0; i < 8; ++i)
            rwc[i] = *(const us8*)(Wct + (size_t)(srow + 32 * i) * 512 + 128 * p + scol);

        // GEMM1: x1 slice [128 rows][128 cols], K = 128
        f32x4 acc1[4][2];
#pragma unroll
        for (int i = 0; i < 4; ++i)
#pragma unroll
            for (int j = 0; j < 2; ++j) acc1[i][j] = (f32x4)(0.0f);
#pragma unroll
        for (int ks = 0; ks < 4; ++ks) {
            const int ko = 32 * ks + lg * 8;
            bf16x8 wfr[2], afr[4];
#pragma unroll
            for (int fn = 0; fn < 2; ++fn)
                wfr[fn] = *(const bf16x8*)&Ws[(32 * wn + 16 * fn + l15) * LD + ko];
#pragma unroll
            for (int fm = 0; fm < 4; ++fm)
                afr[fm] = *(const bf16x8*)&Ag[(64 * wm + 16 * fm + l15) * LD + ko];
#pragma unroll
            for (int fm = 0; fm < 4; ++fm)
#pragma unroll
                for (int fn = 0; fn < 2; ++fn)
                    acc1[fm][fn] = __builtin_amdgcn_mfma_f32_16x16x32_bf16(
                        wfr[fn], afr[fm], acc1[fm][fn], 0, 0, 0);
        }
        __syncthreads();   // Ws reads done

        // write x1 slice (bias+relu, bf16) to X1s
#pragma unroll
        for (int fm = 0; fm < 4; ++fm) {
#pragma unroll
            for (int fn = 0; fn < 2; ++fn) {
                int col1 = 32 * wn + 16 * fn + 4 * lg;         // 0..124
                float4 b4 = *(const float4*)&b1[128 * p + col1];
                f32x4 v = acc1[fm][fn];
                float v0 = fmaxf(v[0] + b4.x, 0.f), v1 = fmaxf(v[1] + b4.y, 0.f);
                float v2 = fmaxf(v[2] + b4.z, 0.f), v3 = fmaxf(v[3] + b4.w, 0.f);
                uint2 o;
                o.x = (unsigned)f2bf(v0) | ((unsigned)f2bf(v1) << 16);
                o.y = (unsigned)f2bf(v2) | ((unsigned)f2bf(v3) << 16);
                *(uint2*)&X1s[(64 * wm + 16 * fm + l15) * LD + col1] = o;
            }
        }
        // Ws <- rwc (Wct slice, 256 rows)
#pragma unroll
        for (int i = 0; i < 8; ++i)
            *(us8*)&Ws[(srow + 32 * i) * LD + scol] = rwc[i];
        // issue next pass's W1t slice loads (land during GEMM2)
        if (p < 3) {
#pragma unroll
            for (int i = 0; i < 4; ++i)
                rw1[i] = *(const us8*)(W1t + (size_t)(128 * (p + 1) + srow + 32 * i) * 128 + scol);
        }
        __syncthreads();

        // GEMM2 accumulate: acc2 += Wct-slice x x1-slice (k = 128)
#pragma unroll
        for (int ks = 0; ks < 4; ++ks) {
            const int ko = 32 * ks + lg * 8;
            bf16x8 wfr[4], xfr[4];
#pragma unroll
            for (int fn = 0; fn < 4; ++fn)
                wfr[fn] = *(const bf16x8*)&Ws[(64 * wn + 16 * fn + l15) * LD + ko];
#pragma unroll
            for (int fm = 0; fm < 4; ++fm)
                xfr[fm] = *(const bf16x8*)&X1s[(64 * wm + 16 * fm + l15) * LD + ko];
#pragma unroll
            for (int fm = 0; fm < 4; ++fm)
#pragma unroll
                for (int fn = 0; fn < 4; ++fn)
                    acc2[fm][fn] = __builtin_amdgcn_mfma_f32_16x16x32_bf16(
                        wfr[fn], xfr[fm], acc2[fm][fn], 0, 0, 0);
        }
    }

    // epilogue: row = bm+64wm+16fm+l15; col = 64wn+16fn+4lg
#pragma unroll
    for (int fm = 0; fm < 4; ++fm) {
        const int row = bm + 64 * wm + 16 * fm + l15;
        if (row >= M) continue;
#pragma unroll
        for (int fn = 0; fn < 4; ++fn) {
            const int col = 64 * wn + 16 * fn + 4 * lg;
            f32x4 v = acc2[fm][fn];
            if (col < 128) {                      // h2 -> bf16
                uint2 o;
                o.x = (unsigned)f2bf(v[0]) | ((unsigned)f2bf(v[1]) << 16);
                o.y = (unsigned)f2bf(v[2]) | ((unsigned)f2bf(v[3]) << 16);
                *(uint2*)(h2b + (size_t)row * 128 + col) = o;
            } else {                              // hres -> fp32
                *(float4*)(xout + (size_t)row * 128 + (col - 128)) =
                    make_float4(v[0], v[1], v[2], v[3]);
            }
        }
    }
}

// ---- head GEMM: A[row] += sum_col relu((xb@Wfc1t)[row][col]+bfc1)*Wfc2 -----

__global__ __launch_bounds__(512) void head_gemm(const u16* __restrict__ A,
                                                 const u16* __restrict__ Bt,
                                                 int M,
                                                 const float* __restrict__ bias,
                                                 const float* __restrict__ w2,
                                                 float* __restrict__ Cf) {
    __shared__ u16 As[128][72];
    __shared__ u16 Bs[256][72];
    const int t = threadIdx.x;
    const int bm = blockIdx.x * 128;
    const int w = t >> 6, lane = t & 63;
    const int wm = w >> 2, wn = w & 3;
    const int l15 = lane & 15, lg = lane >> 4;
    const int srow = t >> 3, scol = (t & 7) * 8;
    const int K = 128;

    f32x4 acc[4][4];
#pragma unroll
    for (int i = 0; i < 4; ++i)
#pragma unroll
        for (int j = 0; j < 4; ++j) acc[i][j] = (f32x4)(0.0f);

    for (int kk = 0; kk < K; kk += 64) {
#pragma unroll
        for (int i = 0; i < 2; ++i) {
            int row = srow + 64 * i;
            us8 v = (us8)(u16)0;
            if (bm + row < M)
                v = *(const us8*)(A + (size_t)(bm + row) * K + kk + scol);
            *(us8*)&As[row][scol] = v;
        }
#pragma unroll
        for (int i = 0; i < 4; ++i) {
            int row = srow + 64 * i;
            *(us8*)&Bs[row][scol] =
                *(const us8*)(Bt + (size_t)row * K + kk + scol);
        }
        __syncthreads();
#pragma unroll
        for (int ks = 0; ks < 2; ++ks) {
            const int ko = 32 * ks + lg * 8;
            bf16x8 bfr[4], afr[4];
#pragma unroll
            for (int fn = 0; fn < 4; ++fn)
                bfr[fn] = *(const bf16x8*)&Bs[64 * wn + 16 * fn + l15][ko];
#pragma unroll
            for (int fm = 0; fm < 4; ++fm)
                afr[fm] = *(const bf16x8*)&As[64 * wm + 16 * fm + l15][ko];
#pragma unroll
            for (int fm = 0; fm < 4; ++fm)
#pragma unroll
                for (int fn = 0; fn < 4; ++fn)
                    acc[fm][fn] = __builtin_amdgcn_mfma_f32_16x16x32_bf16(
                        bfr[fn], afr[fm], acc[fm][fn], 0, 0, 0);
        }
        __syncthreads();
    }

    float4 bl4[4], wl4[4];
#pragma unroll
    for (int fn = 0; fn < 4; ++fn) {
        int c = 64 * wn + 16 * fn + 4 * lg;
        bl4[fn] = *(const float4*)&bias[c];
        wl4[fn] = *(const float4*)&w2[c];
    }
#pragma unroll
    for (int fm = 0; fm < 4; ++fm) {
        float p = 0.f;
#pragma unroll
        for (int fn = 0; fn < 4; ++fn) {
            p += fmaxf(acc[fm][fn][0] + bl4[fn].x, 0.f) * wl4[fn].x;
            p += fmaxf(acc[fm][fn][1] + bl4[fn].y, 0.f) * wl4[fn].y;
            p += fmaxf(acc[fm][fn][2] + bl4[fn].z, 0.f) * wl4[fn].z;
            p += fmaxf(acc[fm][fn][3] + bl4[fn].w, 0.f) * wl4[fn].w;
        }
        p += __shfl_xor(p, 16);
        p += __shfl_xor(p, 32);
        int row = bm + 64 * wm + 16 * fm + l15;
        if (lane < 16 && row < M) atomicAdd(&Cf[row], p);
    }
}

// ---------------------------------------------------------------------------

extern "C" void kernel_launch(void* const* d_in, const int* in_sizes, int n_in,
                              void* d_out, int out_size, void* d_ws, size_t ws_size,
                              hipStream_t stream) {
    const float* emb  = (const float*)d_in[0];
    const int*   eidx = (const int*)d_in[1];
    const float* W1   = (const float*)d_in[2];
    const float* b1   = (const float*)d_in[3];
    const float* W2   = (const float*)d_in[4];
    const float* b2   = (const float*)d_in[5];
    const float* Wres = (const float*)d_in[6];
    const float* bres = (const float*)d_in[7];
    const float* Wfc1 = (const float*)d_in[8];
    const float* bfc1 = (const float*)d_in[9];
    const float* Wfc2 = (const float*)d_in[10];
    const float* bfc2 = (const float*)d_in[11];

    const int N = in_sizes[0] / 128;
    const int E = in_sizes[1] / 2;
    const int* srcv = eidx;
    const int* dstv = eidx + E;

    float* out  = (float*)d_out;
    float* xout = out;                       // [N,128]
    float* Aout = out + (size_t)N * 128;     // [N]

    // ---- workspace layout ----
    char* p = (char*)d_ws;
    float* dinv  = (float*)p;            p += (size_t)N * 4;
    float* csr_w = (float*)p;            p += (size_t)E * 4;
    u16*  embb   = (u16*)p;              p += (size_t)N * 128 * 2;   // flat [N][128]
    u16*  aggEb  = (u16*)p;              p += (size_t)N * 128 * 2;   // flat [N][128]
    u16*  h2b    = (u16*)p;              p += (size_t)N * 128 * 2;   // flat [N][128]
    u16*  xb     = (u16*)p;              p += (size_t)N * 128 * 2;   // flat [N][128]
    u16*  W1t    = (u16*)p;              p += (size_t)512 * 128 * 2;
    u16*  Wct    = (u16*)p;              p += (size_t)256 * 512 * 2;
    u16*  Wfc1t  = (u16*)p;              p += (size_t)256 * 128 * 2;
    int*  cnt     = (int*)p;             p += (size_t)N * 4;
    int*  excl    = (int*)p;             p += (size_t)N * 4;
    int*  rowptr  = (int*)p;             p += (size_t)(N + 1) * 4;
    int*  cursor  = (int*)p;             p += (size_t)N * 4;
    int*  bsum    = (int*)p;             p += 256 * 4;
    int*  csr_src = (int*)p;             p += (size_t)E * 4;

    const int T  = 256;
    const int nb = cdiv_ll(N, 256);      // <= 256 required by scanC2

    // 1) fused setup (also zeroes cnt, inits Aout=bfc2)
    const long long setup_work = (long long)N * 32 + 512 * 128 + 256 * 512
                               + 256 * 128 + (long long)N + (long long)N;
    setup_kernel<<<cdiv_ll(setup_work, T), T, 0, stream>>>(
        emb, W1, W2, Wres, Wfc1, bfc2, embb, W1t, Wct, Wfc1t, cnt, Aout, N);

    // 2) CSR build + dinv
    hist_kernel<<<cdiv_ll(E, T), T, 0, stream>>>(dstv, cnt, E);
    scanA_kernel<<<nb, T, 0, stream>>>(cnt, excl, bsum, N);
    scanC2_kernel<<<nb, T, 0, stream>>>(excl, bsum, cnt, rowptr, cursor, dinv, N, E);
    fill_kernel<<<cdiv_ll(E, T), T, 0, stream>>>(srcv, dstv, dinv, cursor, csr_src, csr_w, E);

    // 3) aggE = S @ emb  (flat bf16)
    aggb_kernel<<<cdiv_ll((long long)N * 64, T), T, 0, stream>>>(
        embb, rowptr, csr_src, csr_w, dinv, aggEb, N);

    // 4) fused GEMM1+GEMM2: h2 = relu(aggE@W1+b1)@W2, hres = relu(...)@Wres
    const size_t lds12 = (size_t)(128 * 136 + 256 * 136 + 128 * 136) * sizeof(u16);
    mgemm12<<<cdiv_ll(N, 128), 512, lds12, stream>>>(
        aggEb, W1t, Wct, b1, N, h2b, xout);

    // 5) fused: x = relu(S@h2 + b2) + hres + bres -> xout (fp32) + xb (bf16)
    aggfin_kernel<<<cdiv_ll((long long)N * 64, T), T, 0, stream>>>(
        h2b, rowptr, csr_src, csr_w, dinv, b2, bres, xout, xb, N);

    // 6) head: A += sum relu(xb@Wfc1t + bfc1) * Wfc2  (A pre-init to bfc2)
    head_gemm<<<cdiv_ll(N, 128), 512, 0, stream>>>(
        xb, Wfc1t, N, bfc1, Wfc2, Aout);
}